// Round 12
// baseline (440.870 us; speedup 1.0000x reference)
//
#include <hip/hip_runtime.h>
#include <stdint.h>

#define Mdim 8192
#define Ndim 4096
#define Kdim 4096

#define BM 256
#define BN 256
#define BK 64
#define NT2 (Kdim / BK)   // 64 K-tiles

typedef float f32x4 __attribute__((ext_vector_type(4)));
typedef __bf16 bf16x8 __attribute__((ext_vector_type(8)));
typedef unsigned short ushort_t;

#define FMAXC 3.3858093490333422e+38f  // FLT_MAX * (1 - 0.005)

__device__ __forceinline__ ushort_t f2bf(float f) {
    unsigned u = __float_as_uint(f);
    u += 0x7fffu + ((u >> 16) & 1u);   // round-to-nearest-even
    return (ushort_t)(u >> 16);
}

__device__ __forceinline__ void gload_lds16(const void* g, void* l) {
    __builtin_amdgcn_global_load_lds(
        (const __attribute__((address_space(1))) uint32_t*)g,
        (__attribute__((address_space(3))) uint32_t*)(uint32_t)(uintptr_t)l,
        16, 0, 0);
}

#define SGB(mask, n) __builtin_amdgcn_sched_group_barrier(mask, n, 0)

// ---------------------------------------------------------------------------
// Kernel 1: dequant + CSR outliers -> bf16 weight, FRAGMENT-PACKED layout:
//   packed[kb][n] (uint4) = W[n][kb*8 .. kb*8+8) as 8 bf16.  (kb = k/8)
// One global_load_dwordx4 in the GEMM then yields a whole B-fragment per
// lane, fully coalesced. Store here is a 16B scatter (stride 64 KB) -- B is
// only 32 MB, ~+10us. Everything else unchanged from the verified kernel.
// ---------------------------------------------------------------------------
__global__ __launch_bounds__(128) void dequant_kernel(
        const int* __restrict__ qw, const float* __restrict__ lut,
        const int* __restrict__ rows, const int* __restrict__ cols,
        const float* __restrict__ vals, ushort_t* __restrict__ w16) {
    __shared__ float wrow[128 * 33];
    __shared__ float slut[16];
    const int o = blockIdx.x;
    const int t = threadIdx.x;

    if (t < 16) slut[t] = lut[o * 16 + t];
    __syncthreads();

    const int q0 = qw[0 * Ndim * 128 + o * 128 + t];
    const int q1 = qw[1 * Ndim * 128 + o * 128 + t];
    const int q2 = qw[2 * Ndim * 128 + o * 128 + t];
    const int q3 = qw[3 * Ndim * 128 + o * 128 + t];
    float* dst = &wrow[t * 33];
#pragma unroll
    for (int j = 0; j < 32; ++j) {
        int idx = (((q0 >> j) & 1) << 3) | (((q1 >> j) & 1) << 2) |
                  (((q2 >> j) & 1) << 1) | ((q3 >> j) & 1);
        dst[j] = slut[idx];
    }
    __syncthreads();

    const int beg = rows[o], end = rows[o + 1];
    for (int k = beg + t; k < end; k += 128) {
        int c = cols[k];
        atomicAdd(&wrow[c + (c >> 5)], vals[k]);
    }
    __syncthreads();

    __align__(16) ushort_t tmp[32];
#pragma unroll
    for (int j = 0; j < 32; ++j) tmp[j] = f2bf(dst[j]);
    const uint4* srcg = (const uint4*)tmp;
    uint4* base = (uint4*)w16;                 // packed: uint4 idx = kb*4096 + n
#pragma unroll
    for (int c4 = 0; c4 < 4; ++c4)             // this thread: kb = 4t+c4, n = o
        base[(size_t)(4 * t + c4) * 4096 + o] = srcg[c4];
}

// ---------------------------------------------------------------------------
// Kernel 2: x f32 -> bf16 row-major. Unchanged (HBM-bound, ~30 us).
// ---------------------------------------------------------------------------
__global__ __launch_bounds__(256) void convx_kernel(
        const float* __restrict__ x, ushort_t* __restrict__ y) {
    size_t i = ((size_t)blockIdx.x * 256 + threadIdx.x) * 8;
    float4 a = *(const float4*)(x + i);
    float4 b = *(const float4*)(x + i + 4);
    __align__(16) ushort_t r[8] = {f2bf(a.x), f2bf(a.y), f2bf(a.z), f2bf(a.w),
                                   f2bf(b.x), f2bf(b.y), f2bf(b.z), f2bf(b.w)};
    *(uint4*)(y + i) = *(const uint4*)r;
}

// ---------------------------------------------------------------------------
// Kernel 3: bf16 GEMM, 256x256, BK=64.  Operand split to unload the LDS port
// (R9's measured bottleneck: LDS 256KB/tile ~2300cyc SERIAL with MFMA 2066):
//   A: LDS double-buffer (2 x 32 KB), R9's verified zero-conflict swizzle,
//      staged via global_load_lds. LDS/tile now 160 KB (~1800 cyc) < MFMA.
//   B: FRAGMENT-PACKED global->register, one dwordx4 per lane per fragment
//      (coalesced 4x256B segments; L2/L3-served; 2x wave redundancy = 2 GB),
//      register-double-buffered ONE TILE (~2300 cyc) ahead -> latency hidden;
//      B dependencies ride the compiler's per-register counted vmcnt.
// Per tile/wave: 4 gload_lds + 8 global_load + 16 ds_read + 64 MFMA; SGB
// weave {VMEM 12}{1 DS,4 MFMA}x16; manual wait = vmcnt(8) only (A-stage
// landed; B(t+1) 8 loads stay in flight). One barrier per tile.
// Correctness: textbook A-dbuf (stage(t+1) writes buf (t+1)&1, consumed in
// t-1 before its barrier); vmcnt(8) retires the 4 A-stage loads (issued
// before the 8 B loads, in-order retirement) -> A(t+1) resident at barrier.
// ---------------------------------------------------------------------------
__global__ __launch_bounds__(512, 2) void gemm_kernel(
        const ushort_t* __restrict__ A, const ushort_t* __restrict__ Bp,
        const float* __restrict__ bias, float* __restrict__ C) {
    __shared__ __align__(16) char lds[65536];   // A dbuf only

    // XCD swizzle, bn-fastest: blocks on one XCD share A panels via L2,
    // stream packed B via L2/L3. nwg=512 (%8==0).
    const int wgid = blockIdx.x;
    const int swz = (wgid & 7) * 64 + (wgid >> 3);
    const int bn = swz & 15, bm = swz >> 4;
    const int m0 = bm * BM, n0 = bn * BN;

    const int tid = threadIdx.x;
    const int lane = tid & 63, wid = tid >> 6;
    const int wr = wid >> 2, wc = wid & 3;       // 2M x 4N wave grid
    const int fr = lane & 15, kg = lane >> 4;

    // ---- A staging geometry (inverse-swizzled source, linear LDS dest)
    const int srow = tid >> 3;
    const int scol = (((tid & 7) ^ (srow & 7)) * 8);
    const ushort_t* pAs = A + (size_t)(m0 + srow) * Kdim + scol;

    // ---- A ds_read swizzled offsets per k-step (row stride 128 B)
    const int off0 = fr * 128 + (((kg) ^ (fr & 7)) << 4);
    const int off1 = fr * 128 + (((4 | kg) ^ (fr & 7)) << 4);

    // ---- B packed per-lane base (uint4 units): idx = kb*4096 + n
    const uint4* pBt = (const uint4*)Bp + (size_t)kg * 4096 + (n0 + wc * 64 + fr);

    f32x4 acc[8][4];
#pragma unroll
    for (int i = 0; i < 8; ++i)
#pragma unroll
        for (int j = 0; j < 4; ++j) acc[i][j] = (f32x4){0.f, 0.f, 0.f, 0.f};

    auto stageA = [&](int buf) {
        char* d = lds + buf * 32768 + tid * 16;
#pragma unroll
        for (int j = 0; j < 4; ++j)
            gload_lds16(pAs + (size_t)j * 64 * Kdim, d + j * 8192);
        pAs += BK;
    };
    auto loadB = [&](bf16x8 (&Bn)[2][4], const uint4* p) {
#pragma unroll
        for (int ks = 0; ks < 2; ++ks)
#pragma unroll
            for (int nf = 0; nf < 4; ++nf)
                Bn[ks][nf] = *(const bf16x8*)(p + ks * 4 * 4096 + nf * 16);
    };

    // one K-tile: MFMA tile t from A-LDS(buf bufi) x Bc regs; stage A(t+1)
    // into bufn; load B(t+1) into Bn; vmcnt(8); barrier.
    auto halfTile = [&](int bufi, int bufn, bf16x8 (&Bc)[2][4], bf16x8 (&Bn)[2][4]) {
        const char* Ab = lds + bufi * 32768;
        stageA(bufn);
        loadB(Bn, pBt + 8 * 4096);                 // tile t+1
        pBt += 8 * 4096;

        bf16x8 FA0[8], FA1[8];
#pragma unroll
        for (int m = 0; m < 8; ++m)
            FA0[m] = *(const bf16x8*)(Ab + wr * 16384 + m * 2048 + off0);
#pragma unroll
        for (int m = 0; m < 8; ++m)
            FA1[m] = *(const bf16x8*)(Ab + wr * 16384 + m * 2048 + off1);

        __builtin_amdgcn_s_setprio(1);
#pragma unroll
        for (int m = 0; m < 8; ++m)
#pragma unroll
            for (int n = 0; n < 4; ++n)
                acc[m][n] = __builtin_amdgcn_mfma_f32_16x16x32_bf16(
                    FA0[m], Bc[0][n], acc[m][n], 0, 0, 0);
#pragma unroll
        for (int m = 0; m < 8; ++m)
#pragma unroll
            for (int n = 0; n < 4; ++n)
                acc[m][n] = __builtin_amdgcn_mfma_f32_16x16x32_bf16(
                    FA1[m], Bc[1][n], acc[m][n], 0, 0, 0);
        __builtin_amdgcn_s_setprio(0);

        // emission: all 12 VMEM first (max latency headroom), then weave
        // {1 ds_read : 4 MFMA} x16 so the DS port drains under the MFMA pipe.
        SGB(0x30, 12);
#pragma unroll
        for (int i = 0; i < 16; ++i) { SGB(0x100, 1); SGB(0x8, 4); }

        asm volatile("s_waitcnt vmcnt(8)");    // A(t+1) landed; B(t+1) in flight
        __builtin_amdgcn_sched_barrier(0);
        __builtin_amdgcn_s_barrier();
    };

    // ---- prologue: stage A(0); load B(0); wait A(0); barrier
    bf16x8 Bca[2][4], Bcb[2][4];
    stageA(0);
    loadB(Bca, pBt);                               // tile 0
    asm volatile("s_waitcnt vmcnt(8)");            // 4 A + 8 B out -> A landed
    __builtin_amdgcn_sched_barrier(0);
    __builtin_amdgcn_s_barrier();

    // ===== main loop: tiles 0..61 =====
#pragma unroll 1
    for (int it = 0; it < (NT2 - 2) / 2; ++it) {
        halfTile(0, 1, Bca, Bcb);
        halfTile(1, 0, Bcb, Bca);
    }
    // tile 62 (buf 0): stages A(63), loads B(63) -> Bcb
    halfTile(0, 1, Bca, Bcb);

    // ===== tail: tile 63 (buf 1, Bcb; no staging, no barrier) =====
    {
        const char* Ab = lds + 32768;
        bf16x8 FA0[8], FA1[8];
#pragma unroll
        for (int m = 0; m < 8; ++m)
            FA0[m] = *(const bf16x8*)(Ab + wr * 16384 + m * 2048 + off0);
#pragma unroll
        for (int m = 0; m < 8; ++m)
            FA1[m] = *(const bf16x8*)(Ab + wr * 16384 + m * 2048 + off1);
#pragma unroll
        for (int m = 0; m < 8; ++m)
#pragma unroll
            for (int n = 0; n < 4; ++n)
                acc[m][n] = __builtin_amdgcn_mfma_f32_16x16x32_bf16(
                    FA0[m], Bcb[0][n], acc[m][n], 0, 0, 0);
#pragma unroll
        for (int m = 0; m < 8; ++m)
#pragma unroll
            for (int n = 0; n < 4; ++n)
                acc[m][n] = __builtin_amdgcn_mfma_f32_16x16x32_bf16(
                    FA1[m], Bcb[1][n], acc[m][n], 0, 0, 0);
    }

    // ---- epilogue: C/D layout col = lane&15, row = (lane>>4)*4 + reg
    const int rg = lane >> 4;
#pragma unroll
    for (int nf = 0; nf < 4; ++nf) {
        const int col = n0 + wc * 64 + nf * 16 + fr;
        const float bv = bias[col];
#pragma unroll
        for (int mf = 0; mf < 8; ++mf) {
            const int row = m0 + wr * 128 + mf * 16 + rg * 4;
            float* outp = C + (size_t)row * Ndim + col;
#pragma unroll
            for (int j = 0; j < 4; ++j) {
                float v = acc[mf][nf][j] + bv;
                v = fminf(fmaxf(v, -FMAXC), FMAXC);
                outp[(size_t)j * Ndim] = v;
            }
        }
    }
}

extern "C" void kernel_launch(void* const* d_in, const int* in_sizes, int n_in,
                              void* d_out, int out_size, void* d_ws, size_t ws_size,
                              hipStream_t stream) {
    const float* x    = (const float*)d_in[0];
    const int*   qw   = (const int*)d_in[1];
    const float* lut  = (const float*)d_in[2];
    const int*   rows = (const int*)d_in[3];
    const int*   cols = (const int*)d_in[4];
    const float* vals = (const float*)d_in[5];
    const float* bias = (const float*)d_in[6];
    float* out = (float*)d_out;

    ushort_t* x16 = (ushort_t*)d_ws;                       // 64 MiB (row-major)
    ushort_t* w16 = x16 + (size_t)Mdim * Kdim;             // 32 MiB (packed)

    hipLaunchKernelGGL(dequant_kernel, dim3(Ndim), dim3(128), 0, stream,
                       qw, lut, rows, cols, vals, w16);
    hipLaunchKernelGGL(convx_kernel, dim3((Mdim * Kdim) / (256 * 8)), dim3(256), 0, stream,
                       x, x16);
    hipLaunchKernelGGL(gemm_kernel, dim3((Mdim / BM) * (Ndim / BN)), dim3(512), 0, stream,
                       x16, w16, bias, out);
}

// Round 13
// 321.405 us; speedup vs baseline: 1.3717x; 1.3717x over previous
//
#include <hip/hip_runtime.h>
#include <stdint.h>

#define Mdim 8192
#define Ndim 4096
#define Kdim 4096

#define BM 256
#define BN 128
#define BK 32
#define NT (Kdim / BK)   // 128 K-tiles

typedef float f32x4 __attribute__((ext_vector_type(4)));
typedef __bf16 bf16x8 __attribute__((ext_vector_type(8)));
typedef unsigned short ushort_t;

#define FMAXC 3.3858093490333422e+38f  // FLT_MAX * (1 - 0.005)

__device__ __forceinline__ ushort_t f2bf(float f) {
    unsigned u = __float_as_uint(f);
    u += 0x7fffu + ((u >> 16) & 1u);   // round-to-nearest-even
    return (ushort_t)(u >> 16);
}

__device__ __forceinline__ void gload_lds16(const void* g, void* l) {
    __builtin_amdgcn_global_load_lds(
        (const __attribute__((address_space(1))) uint32_t*)g,
        (__attribute__((address_space(3))) uint32_t*)(uint32_t)(uintptr_t)l,
        16, 0, 0);
}

#define SGB(mask, n) __builtin_amdgcn_sched_group_barrier(mask, n, 0)

// ---------------------------------------------------------------------------
// Kernel 1: dequant + CSR outliers -> bf16 weight row, ROW-MAJOR (R9 layout,
// verified; R12's packed layout caused 64B-line RMW write amplification).
// ---------------------------------------------------------------------------
__global__ __launch_bounds__(128) void dequant_kernel(
        const int* __restrict__ qw, const float* __restrict__ lut,
        const int* __restrict__ rows, const int* __restrict__ cols,
        const float* __restrict__ vals, ushort_t* __restrict__ w16) {
    __shared__ float wrow[128 * 33];
    __shared__ float slut[16];
    const int o = blockIdx.x;
    const int t = threadIdx.x;

    if (t < 16) slut[t] = lut[o * 16 + t];
    __syncthreads();

    const int q0 = qw[0 * Ndim * 128 + o * 128 + t];
    const int q1 = qw[1 * Ndim * 128 + o * 128 + t];
    const int q2 = qw[2 * Ndim * 128 + o * 128 + t];
    const int q3 = qw[3 * Ndim * 128 + o * 128 + t];
    float* dst = &wrow[t * 33];
#pragma unroll
    for (int j = 0; j < 32; ++j) {
        int idx = (((q0 >> j) & 1) << 3) | (((q1 >> j) & 1) << 2) |
                  (((q2 >> j) & 1) << 1) | ((q3 >> j) & 1);
        dst[j] = slut[idx];
    }
    __syncthreads();

    const int beg = rows[o], end = rows[o + 1];
    for (int k = beg + t; k < end; k += 128) {
        int c = cols[k];
        atomicAdd(&wrow[c + (c >> 5)], vals[k]);
    }
    __syncthreads();

    __align__(16) ushort_t tmp[32];
#pragma unroll
    for (int j = 0; j < 32; ++j) tmp[j] = f2bf(dst[j]);
    uint4* dstg = (uint4*)(w16 + (size_t)o * Kdim + t * 32);
    const uint4* srcg = (const uint4*)tmp;
#pragma unroll
    for (int j = 0; j < 4; ++j) dstg[j] = srcg[j];
}

// ---------------------------------------------------------------------------
// Kernel 2: x f32 -> bf16. Unchanged (HBM-bound, ~30 us at ~6.4 TB/s).
// ---------------------------------------------------------------------------
__global__ __launch_bounds__(256) void convx_kernel(
        const float* __restrict__ x, ushort_t* __restrict__ y) {
    size_t i = ((size_t)blockIdx.x * 256 + threadIdx.x) * 8;
    float4 a = *(const float4*)(x + i);
    float4 b = *(const float4*)(x + i + 4);
    __align__(16) ushort_t r[8] = {f2bf(a.x), f2bf(a.y), f2bf(a.z), f2bf(a.w),
                                   f2bf(b.x), f2bf(b.y), f2bf(b.z), f2bf(b.w)};
    *(uint4*)(y + i) = *(const uint4*)r;
}

// ---------------------------------------------------------------------------
// Kernel 3: bf16 GEMM, 256x128 tile, BK=32, LDS dbuf 48 KiB -> 2 BLOCKS/CU.
// The occupancy play: rounds 4-11 proved a single barrier-locked block
// serializes read-latency + drain + barrier-skew against the MFMA pipe with
// nothing to hide them. Two independent blocks per CU (16 waves, 4/SIMD)
// anti-phase naturally: one block's MFMA clusters cover the other's drains.
//   8 waves (4M x 2N), wave tile 64x64, acc[4][4] (64 AGPR) + 8 frags
//   (32 VGPR) -> ~115 VGPR, below the 128 occupancy cliff
//   (__launch_bounds__(512,4) pins the allocator).
//   Verified paired-row zero-conflict swizzle (R3-R9): byte(row,ks) =
//   (row>>1)*128 + ((((row&1)<<2)|ks) ^ ((row>>1)&7))*16, realized as
//   linear gload_lds dest + inverse-swizzled global source + swizzled read.
// Per tile: stage 3 VMEM (A 2, B 1) -> 8 ds_read_b128 -> 16 MFMA (setprio) ->
// vmcnt(0) -> s_barrier.  Textbook dbuf correctness.
// ---------------------------------------------------------------------------
__global__ __launch_bounds__(512, 4) void gemm_kernel(
        const ushort_t* __restrict__ A, const ushort_t* __restrict__ Bw,
        const float* __restrict__ bias, float* __restrict__ C) {
    __shared__ __align__(16) char lds[49152];   // buf d: A @d*24576, B @+16384

    // XCD swizzle, bn-fastest: an XCD's ~64 concurrent blocks span 2 bm
    // (A pair = 4 MiB -> L2-resident) x all bn; B (32 MiB) served by L3.
    const int wgid = blockIdx.x;                 // nwg = 1024 (%8==0)
    const int swz = (wgid & 7) * 128 + (wgid >> 3);
    const int bn = swz & 31, bm = swz >> 5;
    const int m0 = bm * BM, n0 = bn * BN;

    const int tid = threadIdx.x;
    const int lane = tid & 63, wid = tid >> 6;
    const int wr = wid >> 1, wc = wid & 1;       // 4M x 2N wave grid
    const int fr = lane & 15, kg = lane >> 4;

    // ---- staging geometry (inverse-swizzled global source, linear LDS dest)
    const int sline = tid >> 3;
    const int slot = (tid & 7) ^ (sline & 7);
    const int srow0 = (sline << 1) + (slot >> 2);          // rows 0..127 (+128)
    const int skel = (slot & 3) * 8;                       // k elements
    const ushort_t* gA = A + (size_t)(m0 + srow0) * Kdim + skel;
    const ushort_t* gB = Bw + (size_t)(n0 + srow0) * Kdim + skel;

    // ---- ds_read lane offset (row = 16-aligned base + fr, kslot = kg)
    const int offL = (fr >> 1) * 128 + (((((fr & 1) << 2) | kg) ^ (fr >> 1)) << 4);

    f32x4 acc[4][4];
#pragma unroll
    for (int i = 0; i < 4; ++i)
#pragma unroll
        for (int j = 0; j < 4; ++j) acc[i][j] = (f32x4){0.f, 0.f, 0.f, 0.f};

    auto stage = [&](int buf, int t1) {
        const ushort_t* sa = gA + (size_t)t1 * BK;
        const ushort_t* sb = gB + (size_t)t1 * BK;
        char* d = lds + buf * 24576 + tid * 16;
        gload_lds16(sa, d);                                // A rows 0..127
        gload_lds16(sa + (size_t)128 * Kdim, d + 8192);    // A rows 128..255
        gload_lds16(sb, d + 16384);                        // B rows 0..127
    };

    // ---- prologue: stage tile 0 -> buf 0
    stage(0, 0);
    asm volatile("s_waitcnt vmcnt(0)");
    __builtin_amdgcn_sched_barrier(0);
    __builtin_amdgcn_s_barrier();

    // ===== main loop: tiles 0..NT-2, one barrier per tile =====
#pragma unroll 1
    for (int t = 0; t < NT - 1; ++t) {
        const char* Ab = lds + (t & 1) * 24576;
        const char* Bb = Ab + 16384;

        stage((t + 1) & 1, t + 1);

        bf16x8 FA[4], FB[4];
#pragma unroll
        for (int m = 0; m < 4; ++m)
            FA[m] = *(const bf16x8*)(Ab + wr * 4096 + m * 1024 + offL);
#pragma unroll
        for (int n = 0; n < 4; ++n)
            FB[n] = *(const bf16x8*)(Bb + wc * 4096 + n * 1024 + offL);

        __builtin_amdgcn_s_setprio(1);
#pragma unroll
        for (int m = 0; m < 4; ++m)
#pragma unroll
            for (int n = 0; n < 4; ++n)
                acc[m][n] = __builtin_amdgcn_mfma_f32_16x16x32_bf16(
                    FA[m], FB[n], acc[m][n], 0, 0, 0);
        __builtin_amdgcn_s_setprio(0);

        // emission: 3 stage-VMEM first (latency headroom), 8 DS, 16 MFMA
        SGB(0x30, 3);
        SGB(0x100, 8);
        SGB(0x8, 16);

        asm volatile("s_waitcnt vmcnt(0)");    // next tile resident
        __builtin_amdgcn_sched_barrier(0);
        __builtin_amdgcn_s_barrier();
    }

    // ===== tail: tile NT-1 (no staging, no barrier) =====
    {
        const char* Ab = lds + ((NT - 1) & 1) * 24576;
        const char* Bb = Ab + 16384;
        bf16x8 FA[4], FB[4];
#pragma unroll
        for (int m = 0; m < 4; ++m)
            FA[m] = *(const bf16x8*)(Ab + wr * 4096 + m * 1024 + offL);
#pragma unroll
        for (int n = 0; n < 4; ++n)
            FB[n] = *(const bf16x8*)(Bb + wc * 4096 + n * 1024 + offL);
#pragma unroll
        for (int m = 0; m < 4; ++m)
#pragma unroll
            for (int n = 0; n < 4; ++n)
                acc[m][n] = __builtin_amdgcn_mfma_f32_16x16x32_bf16(
                    FA[m], FB[n], acc[m][n], 0, 0, 0);
    }

    // ---- epilogue: C/D layout col = lane&15, row = (lane>>4)*4 + reg
    const int rg = lane >> 4;
#pragma unroll
    for (int nf = 0; nf < 4; ++nf) {
        const int col = n0 + wc * 64 + nf * 16 + fr;
        const float bv = bias[col];
#pragma unroll
        for (int mf = 0; mf < 4; ++mf) {
            const int row = m0 + wr * 64 + mf * 16 + rg * 4;
            float* outp = C + (size_t)row * Ndim + col;
#pragma unroll
            for (int j = 0; j < 4; ++j) {
                float v = acc[mf][nf][j] + bv;
                v = fminf(fmaxf(v, -FMAXC), FMAXC);
                outp[(size_t)j * Ndim] = v;
            }
        }
    }
}

extern "C" void kernel_launch(void* const* d_in, const int* in_sizes, int n_in,
                              void* d_out, int out_size, void* d_ws, size_t ws_size,
                              hipStream_t stream) {
    const float* x    = (const float*)d_in[0];
    const int*   qw   = (const int*)d_in[1];
    const float* lut  = (const float*)d_in[2];
    const int*   rows = (const int*)d_in[3];
    const int*   cols = (const int*)d_in[4];
    const float* vals = (const float*)d_in[5];
    const float* bias = (const float*)d_in[6];
    float* out = (float*)d_out;

    ushort_t* x16 = (ushort_t*)d_ws;                       // 64 MiB
    ushort_t* w16 = x16 + (size_t)Mdim * Kdim;             // 32 MiB

    hipLaunchKernelGGL(dequant_kernel, dim3(Ndim), dim3(128), 0, stream,
                       qw, lut, rows, cols, vals, w16);
    hipLaunchKernelGGL(convx_kernel, dim3((Mdim * Kdim) / (256 * 8)), dim3(256), 0, stream,
                       x, x16);
    hipLaunchKernelGGL(gemm_kernel, dim3((Mdim / BM) * (Ndim / BN)), dim3(512), 0, stream,
                       x16, w16, bias, out);
}

// Round 14
// 290.739 us; speedup vs baseline: 1.5164x; 1.1055x over previous
//
#include <hip/hip_runtime.h>
#include <stdint.h>

#define Mdim 8192
#define Ndim 4096
#define Kdim 4096

#define BM 256
#define BN 256
#define BK 64
#define NT2 (Kdim / BK)   // 64 K-tiles

typedef float f32x4 __attribute__((ext_vector_type(4)));
typedef __bf16 bf16x8 __attribute__((ext_vector_type(8)));
typedef unsigned short ushort_t;

#define FMAXC 3.3858093490333422e+38f  // FLT_MAX * (1 - 0.005)

__device__ __forceinline__ ushort_t f2bf(float f) {
    unsigned u = __float_as_uint(f);
    u += 0x7fffu + ((u >> 16) & 1u);   // round-to-nearest-even
    return (ushort_t)(u >> 16);
}

__device__ __forceinline__ void gload_lds16(const void* g, void* l) {
    __builtin_amdgcn_global_load_lds(
        (const __attribute__((address_space(1))) uint32_t*)g,
        (__attribute__((address_space(3))) uint32_t*)(uint32_t)(uintptr_t)l,
        16, 0, 0);
}

// ---------------------------------------------------------------------------
// Kernel 1: dequant + CSR outliers -> bf16 weight row (row-major, verified).
// ---------------------------------------------------------------------------
__global__ __launch_bounds__(128) void dequant_kernel(
        const int* __restrict__ qw, const float* __restrict__ lut,
        const int* __restrict__ rows, const int* __restrict__ cols,
        const float* __restrict__ vals, ushort_t* __restrict__ w16) {
    __shared__ float wrow[128 * 33];
    __shared__ float slut[16];
    const int o = blockIdx.x;
    const int t = threadIdx.x;

    if (t < 16) slut[t] = lut[o * 16 + t];
    __syncthreads();

    const int q0 = qw[0 * Ndim * 128 + o * 128 + t];
    const int q1 = qw[1 * Ndim * 128 + o * 128 + t];
    const int q2 = qw[2 * Ndim * 128 + o * 128 + t];
    const int q3 = qw[3 * Ndim * 128 + o * 128 + t];
    float* dst = &wrow[t * 33];
#pragma unroll
    for (int j = 0; j < 32; ++j) {
        int idx = (((q0 >> j) & 1) << 3) | (((q1 >> j) & 1) << 2) |
                  (((q2 >> j) & 1) << 1) | ((q3 >> j) & 1);
        dst[j] = slut[idx];
    }
    __syncthreads();

    const int beg = rows[o], end = rows[o + 1];
    for (int k = beg + t; k < end; k += 128) {
        int c = cols[k];
        atomicAdd(&wrow[c + (c >> 5)], vals[k]);
    }
    __syncthreads();

    __align__(16) ushort_t tmp[32];
#pragma unroll
    for (int j = 0; j < 32; ++j) tmp[j] = f2bf(dst[j]);
    uint4* dstg = (uint4*)(w16 + (size_t)o * Kdim + t * 32);
    const uint4* srcg = (const uint4*)tmp;
#pragma unroll
    for (int j = 0; j < 4; ++j) dstg[j] = srcg[j];
}

// ---------------------------------------------------------------------------
// Kernel 2: x f32 -> bf16. Unchanged (HBM-bound, ~30 us).
// ---------------------------------------------------------------------------
__global__ __launch_bounds__(256) void convx_kernel(
        const float* __restrict__ x, ushort_t* __restrict__ y) {
    size_t i = ((size_t)blockIdx.x * 256 + threadIdx.x) * 8;
    float4 a = *(const float4*)(x + i);
    float4 b = *(const float4*)(x + i + 4);
    __align__(16) ushort_t r[8] = {f2bf(a.x), f2bf(a.y), f2bf(a.z), f2bf(a.w),
                                   f2bf(b.x), f2bf(b.y), f2bf(b.z), f2bf(b.w)};
    *(uint4*)(y + i) = *(const uint4*)r;
}

// ---------------------------------------------------------------------------
// Kernel 3: bf16 GEMM, 256x256, BK=64 — FAITHFUL m201 4-phase-per-tile port.
// 8 waves (2M x 4N), wave tile 128x64, acc[8][4]. LDS 128 KiB = 2 bufs x
// 4 K-halves {Ak0,Ak1,Bk0,Bk1}, each a [256][32] tile with the verified
// zero-conflict paired-row swizzle (linear gload_lds dest + inverse-swizzled
// global source + swizzled ds_read).
// Phase p of tile t: {ds_read subtile (4 or 8 b128); stage ONE half of tile
// t+1 (2 gload_lds); s_barrier; lgkmcnt(0); setprio(1); 16 MFMA; setprio(0);
// [vmcnt(4) at P2/P4]; s_barrier}.  Counted vmcnt NEVER 0 in the loop.
// FIFO ledger (per thread, 2 loads/half, stage order Ak0,Bk0,Ak1,Bk1):
//   entering tile t: [Ak1(t),Bk1(t)] outstanding (4).
//   P1 reads Ak0,Bk0(t) [retired by t-1:P4's vmcnt(4)]; +Ak0(t+1) -> 6.
//   P2 reads Ak0(t); +Bk0(t+1) -> 8; vmcnt(4) retires Ak1,Bk1(t); barrier.
//   P3 reads Ak1,Bk1(t) [now resident]; +Ak1(t+1) -> 6.
//   P4 reads Ak1(t); +Bk1(t+1) -> 8; vmcnt(4) retires Ak0,Bk0(t+1); barrier.
// WAR: each stage targets a buffer region whose ds_reads were consumed >=4
// barriers earlier. K-half phases are wave-uniform (M/N halves are not).
// ---------------------------------------------------------------------------
__global__ __launch_bounds__(512, 2) void gemm_kernel(
        const ushort_t* __restrict__ A, const ushort_t* __restrict__ Bw,
        const float* __restrict__ bias, float* __restrict__ C) {
    __shared__ __align__(16) char lds[131072];
    // buf c at c*65536: Ak0 @+0, Ak1 @+16384, Bk0 @+32768, Bk1 @+49152

    // XCD swizzle, bn-fastest (R9): nwg=512 (%8==0)
    const int wgid = blockIdx.x;
    const int swz = (wgid & 7) * 64 + (wgid >> 3);
    const int bn = swz & 15, bm = swz >> 4;
    const int m0 = bm * BM, n0 = bn * BN;

    const int tid = threadIdx.x;
    const int lane = tid & 63, wid = tid >> 6;
    const int wr = wid >> 2, wc = wid & 3;       // 2M x 4N wave grid
    const int fr = lane & 15, kg = lane >> 4;

    // ---- staging geometry (inverse-swizzled global source, linear LDS dest)
    const int sline = tid >> 3;
    const int slot = (tid & 7) ^ (sline & 7);
    const int srow0 = (sline << 1) + (slot >> 2);          // + 128 for chunk 1
    const int skel = (slot & 3) * 8;                       // k elements
    const ushort_t* gA = A + (size_t)(m0 + srow0) * Kdim + skel;
    const ushort_t* gB = Bw + (size_t)(n0 + srow0) * Kdim + skel;

    // ---- ds_read lane offset within a [256][32] half (row base + fr, kslot kg)
    const int offL = (fr >> 1) * 128 + (((((fr & 1) << 2) | kg) ^ (fr >> 1)) << 4);

    f32x4 acc[8][4];
#pragma unroll
    for (int i = 0; i < 8; ++i)
#pragma unroll
        for (int j = 0; j < 4; ++j) acc[i][j] = (f32x4){0.f, 0.f, 0.f, 0.f};

    auto stageHalf = [&](const ushort_t* gsrc, int ldsOff, int koff) {
        char* d = lds + ldsOff + tid * 16;
        gload_lds16(gsrc + koff, d);
        gload_lds16(gsrc + koff + (size_t)128 * Kdim, d + 8192);
    };
    auto readA4 = [&](bf16x8 (&F)[4], int base, int mh) {
#pragma unroll
        for (int m = 0; m < 4; ++m)
            F[m] = *(const bf16x8*)(lds + base + wr * 8192 + (mh * 4 + m) * 1024 + offL);
    };
    auto readB4 = [&](bf16x8 (&F)[4], int base) {
#pragma unroll
        for (int n = 0; n < 4; ++n)
            F[n] = *(const bf16x8*)(lds + base + wc * 4096 + n * 1024 + offL);
    };
    auto mfma16 = [&](int mh, bf16x8 (&FA)[4], bf16x8 (&FB)[4]) {
        __builtin_amdgcn_s_setprio(1);
#pragma unroll
        for (int m = 0; m < 4; ++m)
#pragma unroll
            for (int n = 0; n < 4; ++n)
                acc[mh * 4 + m][n] = __builtin_amdgcn_mfma_f32_16x16x32_bf16(
                    FA[m], FB[n], acc[mh * 4 + m][n], 0, 0, 0);
        __builtin_amdgcn_s_setprio(0);
    };

    // ---- prologue: stage tile 0's four halves in FIFO order; vmcnt(4)
    stageHalf(gA, 0, 0);            // Ak0(0)
    stageHalf(gB, 32768, 0);        // Bk0(0)
    stageHalf(gA, 16384, 32);       // Ak1(0)
    stageHalf(gB, 49152, 32);       // Bk1(0)
    asm volatile("s_waitcnt vmcnt(4)");      // Ak0,Bk0 resident
    __builtin_amdgcn_sched_barrier(0);
    __builtin_amdgcn_s_barrier();

    // ===== main loop: tiles 0..62 (each stages tile t+1) =====
#pragma unroll 1
    for (int t = 0; t < NT2 - 1; ++t) {
        const int cb = (t & 1) * 65536, nb = ((t + 1) & 1) * 65536;
        const int koff = (t + 1) * BK;
        bf16x8 FA[4], FB0[4], FB1[4];

        // ---- P1: read Ak0 m0-3 + Bk0; stage Ak0(t+1); MFMA acc[0-3] k0
        readA4(FA, cb, 0);
        readB4(FB0, cb + 32768);
        stageHalf(gA, nb, koff);
        __builtin_amdgcn_s_barrier();
        asm volatile("s_waitcnt lgkmcnt(0)");
        __builtin_amdgcn_sched_barrier(0);
        mfma16(0, FA, FB0);
        __builtin_amdgcn_s_barrier();

        // ---- P2: read Ak0 m4-7; stage Bk0(t+1); MFMA acc[4-7] k0; vmcnt(4)
        readA4(FA, cb, 1);
        stageHalf(gB, nb + 32768, koff);
        __builtin_amdgcn_s_barrier();
        asm volatile("s_waitcnt lgkmcnt(0)");
        __builtin_amdgcn_sched_barrier(0);
        mfma16(1, FA, FB0);
        asm volatile("s_waitcnt vmcnt(4)");  // Ak1,Bk1(t) resident
        __builtin_amdgcn_sched_barrier(0);
        __builtin_amdgcn_s_barrier();

        // ---- P3: read Ak1 m0-3 + Bk1; stage Ak1(t+1); MFMA acc[0-3] k1
        readA4(FA, cb + 16384, 0);
        readB4(FB1, cb + 49152);
        stageHalf(gA, nb + 16384, koff + 32);
        __builtin_amdgcn_s_barrier();
        asm volatile("s_waitcnt lgkmcnt(0)");
        __builtin_amdgcn_sched_barrier(0);
        mfma16(0, FA, FB1);
        __builtin_amdgcn_s_barrier();

        // ---- P4: read Ak1 m4-7; stage Bk1(t+1); MFMA acc[4-7] k1; vmcnt(4)
        readA4(FA, cb + 16384, 1);
        stageHalf(gB, nb + 49152, koff + 32);
        __builtin_amdgcn_s_barrier();
        asm volatile("s_waitcnt lgkmcnt(0)");
        __builtin_amdgcn_sched_barrier(0);
        mfma16(1, FA, FB1);
        asm volatile("s_waitcnt vmcnt(4)");  // Ak0,Bk0(t+1) resident
        __builtin_amdgcn_sched_barrier(0);
        __builtin_amdgcn_s_barrier();
    }

    // ===== tail: tile 63 (buf 1), no staging =====
    {
        const int cb = ((NT2 - 1) & 1) * 65536;
        bf16x8 FA[4], FB0[4], FB1[4];
        // P1
        readA4(FA, cb, 0);
        readB4(FB0, cb + 32768);
        asm volatile("s_waitcnt lgkmcnt(0)");
        __builtin_amdgcn_sched_barrier(0);
        mfma16(0, FA, FB0);
        // P2
        readA4(FA, cb, 1);
        asm volatile("s_waitcnt lgkmcnt(0)");
        __builtin_amdgcn_sched_barrier(0);
        mfma16(1, FA, FB0);
        asm volatile("s_waitcnt vmcnt(0)");  // Ak1,Bk1(63) resident
        __builtin_amdgcn_sched_barrier(0);
        __builtin_amdgcn_s_barrier();
        // P3
        readA4(FA, cb + 16384, 0);
        readB4(FB1, cb + 49152);
        asm volatile("s_waitcnt lgkmcnt(0)");
        __builtin_amdgcn_sched_barrier(0);
        mfma16(0, FA, FB1);
        // P4
        readA4(FA, cb + 16384, 1);
        asm volatile("s_waitcnt lgkmcnt(0)");
        __builtin_amdgcn_sched_barrier(0);
        mfma16(1, FA, FB1);
    }

    // ---- epilogue: C/D layout col = lane&15, row = (lane>>4)*4 + reg
    const int rg = lane >> 4;
#pragma unroll
    for (int nf = 0; nf < 4; ++nf) {
        const int col = n0 + wc * 64 + nf * 16 + fr;
        const float bv = bias[col];
#pragma unroll
        for (int mf = 0; mf < 8; ++mf) {
            const int row = m0 + wr * 128 + mf * 16 + rg * 4;
            float* outp = C + (size_t)row * Ndim + col;
#pragma unroll
            for (int j = 0; j < 4; ++j) {
                float v = acc[mf][nf][j] + bv;
                v = fminf(fmaxf(v, -FMAXC), FMAXC);
                outp[(size_t)j * Ndim] = v;
            }
        }
    }
}

extern "C" void kernel_launch(void* const* d_in, const int* in_sizes, int n_in,
                              void* d_out, int out_size, void* d_ws, size_t ws_size,
                              hipStream_t stream) {
    const float* x    = (const float*)d_in[0];
    const int*   qw   = (const int*)d_in[1];
    const float* lut  = (const float*)d_in[2];
    const int*   rows = (const int*)d_in[3];
    const int*   cols = (const int*)d_in[4];
    const float* vals = (const float*)d_in[5];
    const float* bias = (const float*)d_in[6];
    float* out = (float*)d_out;

    ushort_t* x16 = (ushort_t*)d_ws;                       // 64 MiB
    ushort_t* w16 = x16 + (size_t)Mdim * Kdim;             // 32 MiB

    hipLaunchKernelGGL(dequant_kernel, dim3(Ndim), dim3(128), 0, stream,
                       qw, lut, rows, cols, vals, w16);
    hipLaunchKernelGGL(convx_kernel, dim3((Mdim * Kdim) / (256 * 8)), dim3(256), 0, stream,
                       x, x16);
    hipLaunchKernelGGL(gemm_kernel, dim3((Mdim / BM) * (Ndim / BN)), dim3(512), 0, stream,
                       x16, w16, bias, out);
}